// Round 24
// baseline (233.521 us; speedup 1.0000x reference)
//
#include <hip/hip_runtime.h>

#define N_Q   6273
#define N_KEY 1569
#define NHEAD 12
#define HD    64
#define DQH   128     // augmented head dim
#define DIMM  768
#define NSP   6272
#define SCALE 0.125f
#define LOG2E 1.44269504f
#define QSC   (SCALE * LOG2E)
#define EPSLN 1e-5f
#define DEFER_THR 11.5f   // 8 nats in log2 units
#define QBLK  160         // 10 waves x 16 q-rows
#define NQT   ((N_Q + QBLK - 1) / QBLK)   // 40 q-tiles per head

typedef __bf16 bf16x8 __attribute__((ext_vector_type(8)));
typedef float  f32x4  __attribute__((ext_vector_type(4)));
typedef unsigned short ushort_t;
typedef unsigned int uint_t;

__device__ __forceinline__ ushort_t f2bf(float f) {
    union { float f; unsigned u; } v; v.f = f;
    unsigned r = (v.u + 0x7FFFu + ((v.u >> 16) & 1u)) >> 16;
    return (ushort_t)r;
}
__device__ __forceinline__ float bf2f(ushort_t b) {
    union { unsigned u; float f; } v; v.u = ((unsigned)b) << 16;
    return v.f;
}
__device__ __forceinline__ ushort_t cvt_native(float f) {
    __bf16 h = (__bf16)f;
    return *(ushort_t*)&h;
}
__device__ __forceinline__ uint_t pk2(float a, float b) {
    return (uint_t)cvt_native(a) | ((uint_t)cvt_native(b) << 16);
}
// raw v_exp_f32: D = 2^S0 (single transcendental op; no libm denorm guards)
__device__ __forceinline__ float fexp2(float x) {
    float r;
    asm("v_exp_f32 %0, %1" : "=v"(r) : "v"(x));
    return r;
}
__device__ __forceinline__ void gload_lds16(const ushort_t* g, ushort_t* l) {
    __builtin_amdgcn_global_load_lds(
        (const __attribute__((address_space(1))) void*)g,
        (__attribute__((address_space(3))) void*)l, 16, 0, 0);
}
// m204 bijective XCD remap: orig block id -> chunked-per-XCD id (nwg any)
__device__ __forceinline__ int xcd_swz(int orig, int nwg) {
    int xcd = orig & 7, j = orig >> 3;
    int q = nwg >> 3, r = nwg & 7;
    return (xcd < r ? xcd * (q + 1) : r * (q + 1) + (xcd - r) * q) + j;
}

// ---------------------------------------------------------------------------
// fp32 -> bf16 convert, 3 sources, contiguous destination. 8 elems/thread.
// ---------------------------------------------------------------------------
__global__ __launch_bounds__(256) void cvt3_bf16(
    const float* __restrict__ s0, const float* __restrict__ s1,
    const float* __restrict__ s2, ushort_t* __restrict__ dst,
    int n0, int n1, int n2)
{
    int total = n0 + n1 + n2;
    int stride = gridDim.x * 256;
    for (int i = blockIdx.x * 256 + threadIdx.x; i < total; i += stride) {
        const float* src; int j;
        if (i < n0)           { src = s0; j = i; }
        else if (i < n0 + n1) { src = s1; j = i - n0; }
        else                  { src = s2; j = i - n0 - n1; }
        const float4* s4 = (const float4*)src + (size_t)j * 2;
        float4 a = s4[0], b = s4[1];
        uint4 o;
        o.x = (unsigned)f2bf(a.x) | ((unsigned)f2bf(a.y) << 16);
        o.y = (unsigned)f2bf(a.z) | ((unsigned)f2bf(a.w) << 16);
        o.z = (unsigned)f2bf(b.x) | ((unsigned)f2bf(b.y) << 16);
        o.w = (unsigned)f2bf(b.z) | ((unsigned)f2bf(b.w) << 16);
        *(uint4*)&dst[(size_t)i * 8] = o;
    }
}

// ---------------------------------------------------------------------------
// Pipelined GEMM: 128x128 tile, BK=64, 8 waves, gload_lds w=16, pre-swizzled
// src, XOR ds_read, XCD remap. MODE 1: qkv scatter (used for qkv only).
// ---------------------------------------------------------------------------
template <int MODE>
__global__ __launch_bounds__(512) void gemm_pipe(
    const ushort_t* __restrict__ A, const ushort_t* __restrict__ B,
    const float* __restrict__ bias, int M,
    float* __restrict__ Cf, ushort_t* __restrict__ qd, ushort_t* __restrict__ kd,
    ushort_t* __restrict__ vd)
{
    __shared__ ushort_t sm[32768];
    const int tid = threadIdx.x;
    const int wave = tid >> 6, lane = tid & 63;
    const int lo = lane & 15, hi = lane >> 4;
    const int nbx = gridDim.x;
    const int lin = xcd_swz(blockIdx.x + blockIdx.y * nbx, nbx * gridDim.y);
    const int bx = lin % nbx, by = lin / nbx;
    const int row0 = by * 128, col0 = bx * 128;
    const int wr = wave >> 2;
    const int wc = wave & 3;
    const int K = DIMM;
    const int NT = K / 64;

    f32x4 acc[4][2];
#pragma unroll
    for (int i = 0; i < 4; ++i)
#pragma unroll
        for (int j = 0; j < 2; ++j)
#pragma unroll
            for (int r = 0; r < 4; ++r) acc[i][j][r] = 0.f;

    const int sr = lane >> 3;
    const int scb = (lane & 7) * 16;

    auto stage = [&](int t) {
        ushort_t* Ab = sm + ((t & 1) ? 16384 : 0);
        ushort_t* Bb = Ab + 8192;
        const int k0 = t * 64;
#pragma unroll
        for (int i = 0; i < 2; ++i) {
            int ch = wave * 2 + i;
            int r = ch * 8 + sr;
            int cbs = scb ^ ((r & 7) << 4);
            int ga = row0 + r; if (ga > M - 1) ga = M - 1;
            gload_lds16(&A[(size_t)ga * K + k0 + (cbs >> 1)], &Ab[ch * 512]);
            gload_lds16(&B[(size_t)(col0 + r) * K + k0 + (cbs >> 1)], &Bb[ch * 512]);
        }
    };

    stage(0);
    for (int t = 0; t < NT; ++t) {
        __syncthreads();
        if (t + 1 < NT) stage(t + 1);
        ushort_t* Ab = sm + ((t & 1) ? 16384 : 0);
        ushort_t* Bb = Ab + 8192;
#pragma unroll
        for (int ks = 0; ks < 2; ++ks) {
            bf16x8 af[4], bfr[2];
#pragma unroll
            for (int s = 0; s < 4; ++s) {
                int ra = wr * 64 + s * 16 + lo;
                int ca = (ks * 64 + hi * 16) ^ ((ra & 7) << 4);
                af[s] = *(const bf16x8*)&Ab[ra * 64 + (ca >> 1)];
            }
#pragma unroll
            for (int s2 = 0; s2 < 2; ++s2) {
                int rb = wc * 32 + s2 * 16 + lo;
                int cb2 = (ks * 64 + hi * 16) ^ ((rb & 7) << 4);
                bfr[s2] = *(const bf16x8*)&Bb[rb * 64 + (cb2 >> 1)];
            }
#pragma unroll
            for (int i = 0; i < 4; ++i)
#pragma unroll
                for (int j = 0; j < 2; ++j)
                    acc[i][j] = __builtin_amdgcn_mfma_f32_16x16x32_bf16(
                        af[i], bfr[j], acc[i][j], 0, 0, 0);
        }
    }

#pragma unroll
    for (int i = 0; i < 4; ++i) {
#pragma unroll
        for (int reg = 0; reg < 4; ++reg) {
            int r = row0 + wr * 64 + i * 16 + hi * 4 + reg;
            if (r >= M) continue;
#pragma unroll
            for (int j = 0; j < 2; ++j) {
                int c = col0 + wc * 32 + j * 16 + lo;
                float val = acc[i][j][reg] + bias[c];
                if (MODE == 0) {
                    Cf[(size_t)r * DIMM + c] = val;
                } else {
                    int which = c / DIMM;
                    int rem = c - which * DIMM;
                    int head = rem >> 6, d = rem & 63;
                    if (which == 0) {
                        qd[((size_t)head * N_Q + r) * DQH + d] = f2bf(val * QSC);
                    } else {
                        ushort_t* dst = (which == 1) ? kd : vd;
                        dst[((size_t)head * N_Q + r) * HD + d] = f2bf(val);
                    }
                }
            }
        }
    }
}

// ---------------------------------------------------------------------------
// proj GEMM, 64x128 tile (594 blocks for better CU packing), pipelined,
// 4 waves (2x2 -> 32x64 per wave), LDS 48KB dbuf -> 3 blocks/CU.
// ---------------------------------------------------------------------------
__global__ __launch_bounds__(256) void gemm_proj64(
    const ushort_t* __restrict__ A, const ushort_t* __restrict__ B,
    const float* __restrict__ bias, int M, float* __restrict__ Cf)
{
    // buffers: [0,12288) and [12288,24576): A 4096 ush + B 8192 ush each
    __shared__ ushort_t sm[24576];
    const int tid = threadIdx.x;
    const int wave = tid >> 6, lane = tid & 63;
    const int lo = lane & 15, hi = lane >> 4;
    const int nbx = gridDim.x;
    const int lin = xcd_swz(blockIdx.x + blockIdx.y * nbx, nbx * gridDim.y);
    const int bx = lin % nbx, by = lin / nbx;
    const int row0 = by * 64, col0 = bx * 128;
    const int wr = wave >> 1;          // 0..1 (32-row stripe)
    const int wc = wave & 1;           // 0..1 (64-col stripe)
    const int K = DIMM;
    const int NT = K / 64;             // 12

    f32x4 acc[2][4];
#pragma unroll
    for (int i = 0; i < 2; ++i)
#pragma unroll
        for (int j = 0; j < 4; ++j)
#pragma unroll
            for (int r = 0; r < 4; ++r) acc[i][j][r] = 0.f;

    const int sr = lane >> 3;
    const int scb = (lane & 7) * 16;

    auto stage = [&](int t) {
        ushort_t* Ab = sm + ((t & 1) ? 12288 : 0);
        ushort_t* Bb = Ab + 4096;
        const int k0 = t * 64;
        // 24 chunks (8 A + 16 B), 6 per wave
#pragma unroll
        for (int i = 0; i < 6; ++i) {
            int ch = wave * 6 + i;
            if (ch < 8) {
                int r = ch * 8 + sr;
                int cbs = scb ^ ((r & 7) << 4);
                int ga = row0 + r; if (ga > M - 1) ga = M - 1;
                gload_lds16(&A[(size_t)ga * K + k0 + (cbs >> 1)], &Ab[ch * 512]);
            } else {
                int tb = ch - 8;
                int r = tb * 8 + sr;
                int cbs = scb ^ ((r & 7) << 4);
                gload_lds16(&B[(size_t)(col0 + r) * K + k0 + (cbs >> 1)], &Bb[tb * 512]);
            }
        }
    };

    stage(0);
    for (int t = 0; t < NT; ++t) {
        __syncthreads();
        if (t + 1 < NT) stage(t + 1);
        ushort_t* Ab = sm + ((t & 1) ? 12288 : 0);
        ushort_t* Bb = Ab + 4096;
#pragma unroll
        for (int ks = 0; ks < 2; ++ks) {
            bf16x8 af[2], bfr[4];
#pragma unroll
            for (int s = 0; s < 2; ++s) {
                int ra = wr * 32 + s * 16 + lo;
                int ca = (ks * 64 + hi * 16) ^ ((ra & 7) << 4);
                af[s] = *(const bf16x8*)&Ab[ra * 64 + (ca >> 1)];
            }
#pragma unroll
            for (int s2 = 0; s2 < 4; ++s2) {
                int rb = wc * 64 + s2 * 16 + lo;
                int cb2 = (ks * 64 + hi * 16) ^ ((rb & 7) << 4);
                bfr[s2] = *(const bf16x8*)&Bb[rb * 64 + (cb2 >> 1)];
            }
#pragma unroll
            for (int i = 0; i < 2; ++i)
#pragma unroll
                for (int j = 0; j < 4; ++j)
                    acc[i][j] = __builtin_amdgcn_mfma_f32_16x16x32_bf16(
                        af[i], bfr[j], acc[i][j], 0, 0, 0);
        }
    }

#pragma unroll
    for (int i = 0; i < 2; ++i) {
#pragma unroll
        for (int reg = 0; reg < 4; ++reg) {
            int r = row0 + wr * 32 + i * 16 + hi * 4 + reg;
            if (r >= M) continue;
#pragma unroll
            for (int j = 0; j < 4; ++j) {
                int c = col0 + wc * 64 + j * 16 + lo;
                Cf[(size_t)r * DIMM + c] = acc[i][j][reg] + bias[c];
            }
        }
    }
}

// ---------------------------------------------------------------------------
// Depthwise 3x3x3 pool (stride 1,2,2, pad 1) + LayerNorm over HD, bf16.
// 8 positions per wave (weight tile amortized 32x per block).
// ---------------------------------------------------------------------------
__global__ __launch_bounds__(256) void pool_ln2(
    const ushort_t* __restrict__ kin, const ushort_t* __restrict__ vin,
    const float* __restrict__ wkk, const float* __restrict__ wkv,
    const float* __restrict__ gk, const float* __restrict__ bk,
    const float* __restrict__ gv, const float* __restrict__ bv,
    ushort_t* __restrict__ kout, ushort_t* __restrict__ vout)
{
    const int is_k = (blockIdx.y == 0);
    const ushort_t* in = is_k ? kin : vin;
    const float* wk = is_k ? wkk : wkv;
    const float* g  = is_k ? gk : gv;
    const float* b  = is_k ? bk : bv;

    __shared__ float ws_s[27][64];
    const int tid = threadIdx.x;
    for (int e = tid; e < 27 * 64; e += 256) {
        int d = e / 27, tap = e - d * 27;
        ws_s[tap][d] = wk[e];
    }
    __syncthreads();

    const int wave = tid >> 6, lane = tid & 63;
    const float gl = g[lane], bl = b[lane];

#pragma unroll 1
    for (int p8 = 0; p8 < 8; ++p8) {
        const int pos = (blockIdx.x * 4 + wave) * 8 + p8;
        if (pos >= NHEAD * N_KEY) continue;
        const int head = pos / N_KEY;
        const int idx = pos - head * N_KEY;
        const ushort_t* base = in + (size_t)head * N_Q * HD;

        float val;
        if (idx == 0) {
            val = bf2f(base[lane]);
        } else {
            int p = idx - 1;
            int t1 = p / 196;
            int h1 = (p / 14) % 14;
            int w1 = p % 14;
            val = 0.f;
            if (t1 >= 1 && t1 <= 6 && h1 >= 1 && w1 >= 1) {
                int n0 = 1 + ((t1 - 1) * 28 + (2 * h1 - 1)) * 28 + (2 * w1 - 1);
#pragma unroll
                for (int dt = 0; dt < 3; ++dt)
#pragma unroll
                    for (int dh = 0; dh < 3; ++dh)
#pragma unroll
                        for (int dw = 0; dw < 3; ++dw) {
                            int n = n0 + (dt * 784) + (dh * 28) + dw;
                            val += bf2f(base[(size_t)n * HD + lane]) *
                                   ws_s[(dt * 3 + dh) * 3 + dw][lane];
                        }
            } else {
#pragma unroll
                for (int dt = 0; dt < 3; ++dt) {
                    int t = t1 + dt - 1;
                    if (t < 0 || t >= 8) continue;
#pragma unroll
                    for (int dh = 0; dh < 3; ++dh) {
                        int h = 2 * h1 + dh - 1;
                        if (h < 0 || h >= 28) continue;
#pragma unroll
                        for (int dw = 0; dw < 3; ++dw) {
                            int w = 2 * w1 + dw - 1;
                            if (w < 0 || w >= 28) continue;
                            int n = 1 + (t * 28 + h) * 28 + w;
                            val += bf2f(base[(size_t)n * HD + lane]) *
                                   ws_s[(dt * 3 + dh) * 3 + dw][lane];
                        }
                    }
                }
            }
        }
        float mu = val;
#pragma unroll
        for (int off = 1; off < 64; off <<= 1) mu += __shfl_xor(mu, off, 64);
        mu *= (1.f / 64.f);
        float dv = val - mu;
        float var = dv * dv;
#pragma unroll
        for (int off = 1; off < 64; off <<= 1) var += __shfl_xor(var, off, 64);
        var *= (1.f / 64.f);
        float ln = dv * rsqrtf(var + EPSLN) * gl + bl;

        if (!is_k) {
            vout[(size_t)pos * HD + lane] = f2bf(ln);
        } else {
            kout[(size_t)pos * DQH + lane] = f2bf(ln);
            float oh = 0.f;
            if (idx > 0) {
                int p = idx - 1;
                int kt = p / 196, kh = (p / 14) % 14, kw = p % 14;
                if ((lane < 14 && lane == kh) ||
                    (lane >= 14 && lane < 28 && (lane - 14) == kw) ||
                    (lane >= 28 && lane < 36 && (lane - 28) == kt))
                    oh = 1.f;
            }
            kout[(size_t)pos * DQH + 64 + lane] = f2bf(oh);
        }
    }
}

// ---------------------------------------------------------------------------
// rel via MFMA: per (head, 128-qs chunk), G = qhat[:,0:64] @ R[125,64]^T
// (one K=64 step), G*8 -> LDS bf16 [128][136], then gather 36 cols/row into
// qhat rel channels. blockIdx.x==49: cls fix (zero head's q-row-0 rel ch).
// ---------------------------------------------------------------------------
__global__ __launch_bounds__(256) void rel_gemm(
    ushort_t* __restrict__ qhat, const float* __restrict__ rh,
    const float* __restrict__ rw, const float* __restrict__ rt)
{
    __shared__ ushort_t sm[17408];
    const int tid = threadIdx.x;
    const int wave = tid >> 6, lane = tid & 63;
    const int lo = lane & 15, hi = lane >> 4;
    const int head = blockIdx.y;

    if (blockIdx.x == 49) {
        if (tid < 64) qhat[((size_t)head * N_Q) * DQH + 64 + tid] = 0;
        return;
    }
    const int qs0 = blockIdx.x * 128;
    ushort_t* Al = sm;
    ushort_t* Bl = sm + 8192;

    const int sr = lane >> 3;
    const int scb = (lane & 7) * 16;
#pragma unroll
    for (int i = 0; i < 4; ++i) {
        int ch = wave * 4 + i;
        int rl = ch * 8 + sr;
        int cbs = scb ^ ((rl & 7) << 4);
        gload_lds16(&qhat[((size_t)head * N_Q + 1 + qs0 + rl) * DQH + (cbs >> 1)],
                    &Al[ch * 512]);
    }
#pragma unroll
    for (int i = 0; i < 4; ++i) {
        int u = tid + i * 256;
        int r = u >> 3, cg = u & 7;
        ushort_t tmp[8];
        if (r < 125) {
            const float* src = (r < 55) ? &rh[r * 64 + cg * 8]
                             : (r < 110) ? &rw[(r - 55) * 64 + cg * 8]
                                         : &rt[(r - 110) * 64 + cg * 8];
#pragma unroll
            for (int k = 0; k < 8; ++k) tmp[k] = f2bf(src[k]);
        } else {
#pragma unroll
            for (int k = 0; k < 8; ++k) tmp[k] = 0;
        }
        *(uint4*)&Bl[r * 64 + ((cg ^ (r & 7)) * 8)] = *(uint4*)tmp;
    }
    __syncthreads();

    f32x4 acc[2][8];
#pragma unroll
    for (int s = 0; s < 2; ++s)
#pragma unroll
        for (int cs = 0; cs < 8; ++cs)
#pragma unroll
            for (int r = 0; r < 4; ++r) acc[s][cs][r] = 0.f;

#pragma unroll
    for (int kk = 0; kk < 2; ++kk) {
        bf16x8 af[2];
#pragma unroll
        for (int s = 0; s < 2; ++s) {
            int ra = wave * 32 + s * 16 + lo;
            int ca = (kk * 32 + hi * 8) ^ ((ra & 7) * 8);
            af[s] = *(const bf16x8*)&Al[ra * 64 + ca];
        }
#pragma unroll
        for (int cs = 0; cs < 8; ++cs) {
            int rb = cs * 16 + lo;
            int cb = (kk * 32 + hi * 8) ^ ((rb & 7) * 8);
            bf16x8 bv = *(const bf16x8*)&Bl[rb * 64 + cb];
            acc[0][cs] = __builtin_amdgcn_mfma_f32_16x16x32_bf16(af[0], bv, acc[0][cs], 0, 0, 0);
            acc[1][cs] = __builtin_amdgcn_mfma_f32_16x16x32_bf16(af[1], bv, acc[1][cs], 0, 0, 0);
        }
    }
    __syncthreads();

#pragma unroll
    for (int s = 0; s < 2; ++s)
#pragma unroll
        for (int cs = 0; cs < 8; ++cs)
#pragma unroll
            for (int reg = 0; reg < 4; ++reg) {
                int rl = wave * 32 + s * 16 + hi * 4 + reg;
                sm[rl * 136 + cs * 16 + lo] = cvt_native(acc[s][cs][reg] * 8.0f);
            }
    __syncthreads();

#pragma unroll 1
    for (int it = 0; it < 18; ++it) {
        int idx = it * 64 + lane;
        int r = idx / 36;
        int j = idx - r * 36;
        int qs = qs0 + wave * 32 + r;
        int t = qs / 784, h = (qs / 28) % 28, w = qs % 28;
        int ridx;
        if (j < 14)      ridx = h - 2 * j + 26;
        else if (j < 28) ridx = 55 + (w - 2 * (j - 14) + 26);
        else             ridx = 110 + (t - (j - 28) + 7);
        ushort_t val = sm[(wave * 32 + r) * 136 + ridx];
        qhat[((size_t)head * N_Q + 1 + qs) * DQH + 64 + j] = val;
    }
}

// ---------------------------------------------------------------------------
// Fused flash attention (R23 exact): pipeline + 4-bit Ks swizzle + setprio +
// hoisted addressing + XCD q-tile remap + raw v_exp softmax + tree max +
// l-via-MFMA with register-constant ones fragment. QBLK=160, 640 thr.
// ---------------------------------------------------------------------------
__global__ __launch_bounds__(640) void attn_mfma(
    const ushort_t* __restrict__ qhat, const ushort_t* __restrict__ khat,
    const ushort_t* __restrict__ vp, ushort_t* __restrict__ aout)
{
    __shared__ ushort_t smem[24576];

    const int tid = threadIdx.x;
    const int wave = tid >> 6, lane = tid & 63;
    const int lo = lane & 15, hi = lane >> 4;
    const int head = blockIdx.y;
    const int q0 = xcd_swz(blockIdx.x, NQT) * QBLK;
    const int qrow = q0 + wave * 16 + lo;

    const ushort_t* khat_h = khat + (size_t)head * N_KEY * DQH;
    const ushort_t* vp_h   = vp + (size_t)head * N_KEY * HD;

    bf16x8 qa[4];
    if (qrow < N_Q) {
        const ushort_t* qpt = &qhat[((size_t)head * N_Q + qrow) * DQH];
#pragma unroll
        for (int j = 0; j < 4; ++j) qa[j] = *(const bf16x8*)&qpt[j * 32 + hi * 8];
    } else {
#pragma unroll
        for (int j = 0; j < 4; ++j)
#pragma unroll
            for (int e = 0; e < 8; ++e) qa[j][e] = (__bf16)0.0f;
    }

    union { ushort_t u16[8]; bf16x8 v; } onesf;
#pragma unroll
    for (int e = 0; e < 8; ++e) onesf.u16[e] = (lo == 0) ? (ushort_t)0x3F80 : 0;

    float m_run = -1e30f;
    f32x4 o[4], olsum;
#pragma unroll
    for (int i = 0; i < 4; ++i)
#pragma unroll
        for (int r = 0; r < 4; ++r) o[i][r] = 0.f;
#pragma unroll
    for (int r = 0; r < 4; ++r) olsum[r] = 0.f;

    const bool oddh = (hi & 1) != 0;
    const bool toph = (hi >> 1) != 0;
    const int NT = (N_KEY + 63) / 64;   // 25

    const int vkey = tid & 63, vd0 = ((tid >> 6) & 7) * 8;
    uint4 vv;

    int ksrd[4][4];
#pragma unroll
    for (int kk = 0; kk < 4; ++kk)
#pragma unroll
        for (int sub = 0; sub < 4; ++sub)
            ksrd[kk][sub] = (sub * 16 + lo) * 128 + ((kk * 32 + hi * 8) ^ (lo * 8));
    int vtrd[2][4];
#pragma unroll
    for (int kh2 = 0; kh2 < 2; ++kh2)
#pragma unroll
        for (int sd = 0; sd < 4; ++sd)
            vtrd[kh2][sd] = (sd * 16 + lo) * 64 + ((kh2 * 32 + hi * 8) ^ ((lo & 7) * 8));
    int vwr[8];
#pragma unroll
    for (int j = 0; j < 8; ++j) vwr[j] = (vd0 + j) * 64 + (vkey ^ (j * 8));

    auto stage = [&](int t) {
        const int m0 = t * 64;
        if (wave < 8) {
            ushort_t* Ksb = smem + ((t & 1) << 13);
#pragma unroll
            for (int i = 0; i < 2; ++i) {
                int ch = wave * 2 + i;
                int kr = ch * 4 + hi;
                int cb = (lo * 16) ^ ((kr & 15) << 4);
                int gm = m0 + kr; if (gm > N_KEY - 1) gm = N_KEY - 1;
                gload_lds16(&khat_h[(gm << 7) + (cb >> 1)], &Ksb[ch * 512]);
            }
            int gm = m0 + vkey; if (gm > N_KEY - 1) gm = N_KEY - 1;
            vv = *(const uint4*)&vp_h[(gm << 6) + vd0];
        }
    };

    stage(0);
#pragma unroll 2
    for (int t = 0; t < NT; ++t) {
        const int m0 = t * 64;
        ushort_t* Ksb = smem + ((t & 1) << 13);
        ushort_t* Vtb = smem + 16384 + ((t & 1) << 12);

        if (wave < 8) {
            ushort_t tmp[8];
            *(uint4*)tmp = vv;
#pragma unroll
            for (int j = 0; j < 8; ++j) Vtb[vwr[j]] = tmp[j];
        }
        __syncthreads();
        if (t + 1 < NT) stage(t + 1);

        f32x4 s[4];
#pragma unroll
        for (int sub = 0; sub < 4; ++sub)
#pragma unroll
            for (int r = 0; r < 4; ++r) s[sub][r] = 0.f;
        __builtin_amdgcn_s_setprio(1);
#pragma unroll
        for (int kk = 0; kk < 4; ++kk) {
#pragma unroll
            for (int sub = 0; sub < 4; ++sub) {
                bf16x8 kf = *(const bf16x8*)&Ksb[ksrd[kk][sub]];
                s[sub] = __builtin_amdgcn_mfma_f32_16x16x32_bf16(kf, qa[kk], s[sub], 0, 0, 0);
            }
        }
        __builtin_amdgcn_s_setprio(0);

        if (m0 + 64 > N_KEY) {
#pragma unroll
            for (int sub = 0; sub < 4; ++sub)
#pragma unroll
                for (int reg = 0; reg < 4; ++reg)
                    if (m0 + sub * 16 + hi * 4 + reg >= N_KEY) s[sub][reg] = -1e30f;
        }

        // tree max (depth 4, max3-fusable)
        float a0 = fmaxf(s[0][0], s[0][1]), a1 = fmaxf(s[0][2], s[0][3]);
        float a2 = fmaxf(s[1][0], s[1][1]), a3 = fmaxf(s[1][2], s[1][3]);
        float a4 = fmaxf(s[2][0], s[2][1]), a5 = fmaxf(s[2][2], s[2][3]);
        float a6 = fmaxf(s[3][0], s[3][1]), a7 = fmaxf(s[3][2], s[3][3]);
        float b0 = fmaxf(a0, a1), b1 = fmaxf(a2, a3);
        float b2 = fmaxf(a4, a5), b3 = fmaxf(a6, a7);
        float rm = fmaxf(fmaxf(b0, b1), fmaxf(b2, b3));
        rm = fmaxf(rm, __shfl_xor(rm, 16));
        rm = fmaxf(rm, __shfl_xor(rm, 32));

        if (__any(rm - m_run > DEFER_THR)) {
            float mnew = fmaxf(m_run, rm);
            float corr = fexp2(m_run - mnew);
#pragma unroll
            for (int sub = 0; sub < 4; ++sub)
#pragma unroll
                for (int reg = 0; reg < 4; ++reg)
                    s[sub][reg] = fexp2(s[sub][reg] - mnew);
            m_run = mnew;
#pragma unroll
            for (int i = 0; i < 4; ++i)
#pragma unroll
                for (int r = 0; r < 4; ++r) o[i][r] *= corr;
            olsum[0] *= corr;
        } else {
#pragma unroll
            for (int sub = 0; sub < 4; ++sub)
#pragma unroll
                for (int reg = 0; reg < 4; ++reg)
                    s[sub][reg] = fexp2(s[sub][reg] - m_run);
        }

#pragma unroll
        for (int kh2 = 0; kh2 < 2; ++kh2) {
            uint_t x0a = pk2(s[2 * kh2][0], s[2 * kh2][1]);
            uint_t x0b = pk2(s[2 * kh2][2], s[2 * kh2][3]);
            uint_t x1a = pk2(s[2 * kh2 + 1][0], s[2 * kh2 + 1][1]);
            uint_t x1b = pk2(s[2 * kh2 + 1][2], s[2 * kh2 + 1][3]);
            uint_t y0a = __shfl_xor(x0a, 16), y0b = __shfl_xor(x0b, 16);
            uint_t y1a = __shfl_xor(x1a, 16), y1b = __shfl_xor(x1b, 16);
            uint_t c0[4] = { oddh ? y0a : x0a, oddh ? y0b : x0b,
                             oddh ? x0a : y0a, oddh ? x0b : y0b };
            uint_t c1[4] = { oddh ? y1a : x1a, oddh ? y1b : x1b,
                             oddh ? x1a : y1a, oddh ? x1b : y1b };
            union { uint_t u[4]; bf16x8 v; } pw;
#pragma unroll
            for (int i2 = 0; i2 < 4; ++i2) {
                uint_t send = oddh ? c0[i2] : c1[i2];
                uint_t f = __shfl_xor(send, 32);
                pw.u[i2] = (toph != oddh) ? f : (oddh ? c1[i2] : c0[i2]);
            }
            __builtin_amdgcn_s_setprio(1);
#pragma unroll
            for (int sub_d = 0; sub_d < 4; ++sub_d) {
                bf16x8 vf = *(const bf16x8*)&Vtb[vtrd[kh2][sub_d]];
                o[sub_d] = __builtin_amdgcn_mfma_f32_16x16x32_bf16(vf, pw.v, o[sub_d], 0, 0, 0);
            }
            olsum = __builtin_amdgcn_mfma_f32_16x16x32_bf16(onesf.v, pw.v, olsum, 0, 0, 0);
            __builtin_amdgcn_s_setprio(0);
        }
    }

    // epilogue
    float lsum = __shfl(olsum[0], lo);
    ushort_t* Ob = smem + wave * (16 * 88);
    __syncthreads();
    float inv = 1.f / lsum;
#pragma unroll
    for (int sub_d = 0; sub_d < 4; ++sub_d)
#pragma unroll
        for (int reg = 0; reg < 4; ++reg)
            Ob[lo * 88 + sub_d * 16 + hi * 4 + reg] = cvt_native(o[sub_d][reg] * inv);
    __syncthreads();
#pragma unroll
    for (int i = 0; i < 2; ++i) {
        int e = lane + i * 64;
        int r = e >> 3, cc = e & 7;
        int gq = q0 + wave * 16 + r;
        if (gq < N_Q) {
            uint4 ov = *(const uint4*)&Ob[r * 88 + cc * 8];
            *(uint4*)&aout[(size_t)gq * DIMM + head * HD + cc * 8] = ov;
        }
    }
}

// ---------------------------------------------------------------------------
extern "C" void kernel_launch(void* const* d_in, const int* in_sizes, int n_in,
                              void* d_out, int out_size, void* d_ws, size_t ws_size,
                              hipStream_t stream)
{
    const float* x      = (const float*)d_in[0];
    const float* qkv_w  = (const float*)d_in[1];
    const float* qkv_b  = (const float*)d_in[2];
    const float* proj_w = (const float*)d_in[3];
    const float* proj_b = (const float*)d_in[4];
    const float* pkw    = (const float*)d_in[5];
    const float* pvw    = (const float*)d_in[6];
    const float* nkg    = (const float*)d_in[7];
    const float* nkb    = (const float*)d_in[8];
    const float* nvg    = (const float*)d_in[9];
    const float* nvb    = (const float*)d_in[10];
    const float* rph    = (const float*)d_in[11];
    const float* rpw    = (const float*)d_in[12];
    const float* rpt    = (const float*)d_in[13];

    const size_t SZ_X     = (size_t)N_Q * DIMM;
    const size_t SZ_QKVW  = (size_t)3 * DIMM * DIMM;
    const size_t SZ_PROJW = (size_t)DIMM * DIMM;
    const size_t SZ_QHAT  = (size_t)NHEAD * N_Q * DQH;
    const size_t SZ_KV    = (size_t)NHEAD * N_Q * HD;
    const size_t SZ_KHAT  = (size_t)NHEAD * N_KEY * DQH;
    const size_t SZ_VPO   = (size_t)NHEAD * N_KEY * HD;

    ushort_t* xb     = (ushort_t*)d_ws;
    ushort_t* qkvwb  = xb + SZ_X;
    ushort_t* projwb = qkvwb + SZ_QKVW;
    ushort_t* qhat   = projwb + SZ_PROJW;
    ushort_t* kb     = qhat + SZ_QHAT;
    ushort_t* vb     = kb + SZ_KV;
    ushort_t* khat   = vb + SZ_KV;
    ushort_t* vpo    = khat + SZ_KHAT;
    ushort_t* aout   = vpo + SZ_VPO;
    float*    outp   = (float*)d_out;

    // 0) convert inputs to bf16
    cvt3_bf16<<<2048, 256, 0, stream>>>(x, qkv_w, proj_w, xb,
                                        (int)(SZ_X / 8), (int)(SZ_QKVW / 8),
                                        (int)(SZ_PROJW / 8));
    // 1) qkv GEMM (pipelined, XCD-swizzled)
    gemm_pipe<1><<<dim3(18, 50), 512, 0, stream>>>(xb, qkvwb, qkv_b, N_Q,
                                                   nullptr, qhat, kb, vb);
    // 2) pool + LN (8 positions/wave)
    pool_ln2<<<dim3((NHEAD * N_KEY + 31) / 32, 2), 256, 0, stream>>>(
        kb, vb, pkw, pvw, nkg, nkb, nvg, nvb, khat, vpo);
    // 3) rel-pos via MFMA GEMM + gather
    rel_gemm<<<dim3(50, NHEAD), 256, 0, stream>>>(qhat, rph, rpw, rpt);
    // 4) fused attention (R23 exact)
    attn_mfma<<<dim3(NQT, NHEAD), 640, 0, stream>>>(qhat, khat, vpo, aout);
    // 5) proj GEMM (64x128 tiles, 594 blocks, pipelined, XCD-swizzled)
    gemm_proj64<<<dim3(6, 99), 256, 0, stream>>>(aout, projwb, proj_b, N_Q, outp);
}

// Round 25
// 230.985 us; speedup vs baseline: 1.0110x; 1.0110x over previous
//
#include <hip/hip_runtime.h>

#define N_Q   6273
#define N_KEY 1569
#define NHEAD 12
#define HD    64
#define DQH   128     // augmented head dim
#define DIMM  768
#define NSP   6272
#define SCALE 0.125f
#define LOG2E 1.44269504f
#define QSC   (SCALE * LOG2E)
#define EPSLN 1e-5f
#define DEFER_THR 11.5f   // 8 nats in log2 units
#define QBLK  160         // 10 waves x 16 q-rows
#define NQT   ((N_Q + QBLK - 1) / QBLK)   // 40 q-tiles per head

typedef __bf16 bf16x8 __attribute__((ext_vector_type(8)));
typedef float  f32x4  __attribute__((ext_vector_type(4)));
typedef unsigned short ushort_t;
typedef unsigned int uint_t;

__device__ __forceinline__ ushort_t f2bf(float f) {
    union { float f; unsigned u; } v; v.f = f;
    unsigned r = (v.u + 0x7FFFu + ((v.u >> 16) & 1u)) >> 16;
    return (ushort_t)r;
}
__device__ __forceinline__ float bf2f(ushort_t b) {
    union { unsigned u; float f; } v; v.u = ((unsigned)b) << 16;
    return v.f;
}
__device__ __forceinline__ ushort_t cvt_native(float f) {
    __bf16 h = (__bf16)f;
    return *(ushort_t*)&h;
}
__device__ __forceinline__ uint_t pk2(float a, float b) {
    return (uint_t)cvt_native(a) | ((uint_t)cvt_native(b) << 16);
}
// raw v_exp_f32: D = 2^S0 (single transcendental op; no libm denorm guards)
__device__ __forceinline__ float fexp2(float x) {
    float r;
    asm("v_exp_f32 %0, %1" : "=v"(r) : "v"(x));
    return r;
}
__device__ __forceinline__ void gload_lds16(const ushort_t* g, ushort_t* l) {
    __builtin_amdgcn_global_load_lds(
        (const __attribute__((address_space(1))) void*)g,
        (__attribute__((address_space(3))) void*)l, 16, 0, 0);
}
// m204 bijective XCD remap: orig block id -> chunked-per-XCD id (nwg any)
__device__ __forceinline__ int xcd_swz(int orig, int nwg) {
    int xcd = orig & 7, j = orig >> 3;
    int q = nwg >> 3, r = nwg & 7;
    return (xcd < r ? xcd * (q + 1) : r * (q + 1) + (xcd - r) * q) + j;
}

// ---------------------------------------------------------------------------
// fp32 -> bf16 convert, 3 sources, contiguous destination. 8 elems/thread.
// ---------------------------------------------------------------------------
__global__ __launch_bounds__(256) void cvt3_bf16(
    const float* __restrict__ s0, const float* __restrict__ s1,
    const float* __restrict__ s2, ushort_t* __restrict__ dst,
    int n0, int n1, int n2)
{
    int total = n0 + n1 + n2;
    int stride = gridDim.x * 256;
    for (int i = blockIdx.x * 256 + threadIdx.x; i < total; i += stride) {
        const float* src; int j;
        if (i < n0)           { src = s0; j = i; }
        else if (i < n0 + n1) { src = s1; j = i - n0; }
        else                  { src = s2; j = i - n0 - n1; }
        const float4* s4 = (const float4*)src + (size_t)j * 2;
        float4 a = s4[0], b = s4[1];
        uint4 o;
        o.x = (unsigned)f2bf(a.x) | ((unsigned)f2bf(a.y) << 16);
        o.y = (unsigned)f2bf(a.z) | ((unsigned)f2bf(a.w) << 16);
        o.z = (unsigned)f2bf(b.x) | ((unsigned)f2bf(b.y) << 16);
        o.w = (unsigned)f2bf(b.z) | ((unsigned)f2bf(b.w) << 16);
        *(uint4*)&dst[(size_t)i * 8] = o;
    }
}

// ---------------------------------------------------------------------------
// Pipelined GEMM (attn-style single-barrier double-buffer): 128x128 tile,
// BK=64, 8 waves (2x4 -> 64x32 per wave), gload_lds w=16, pre-swizzled src,
// XOR-swizzled ds_read, XCD-bijective block remap.
// MODE 0: fp32 row-major store (width DIMM). MODE 1: qkv scatter.
// ---------------------------------------------------------------------------
template <int MODE>
__global__ __launch_bounds__(512) void gemm_pipe(
    const ushort_t* __restrict__ A, const ushort_t* __restrict__ B,
    const float* __restrict__ bias, int M,
    float* __restrict__ Cf, ushort_t* __restrict__ qd, ushort_t* __restrict__ kd,
    ushort_t* __restrict__ vd)
{
    // 64 KB: A0[0,8192) B0[8192,16384) A1[16384,24576) B1[24576,32768) ushorts
    __shared__ ushort_t sm[32768];
    const int tid = threadIdx.x;
    const int wave = tid >> 6, lane = tid & 63;
    const int lo = lane & 15, hi = lane >> 4;
    // XCD-bijective remap of the flattened block id (L2 panel locality)
    const int nbx = gridDim.x;
    const int lin = xcd_swz(blockIdx.x + blockIdx.y * nbx, nbx * gridDim.y);
    const int bx = lin % nbx, by = lin / nbx;
    const int row0 = by * 128, col0 = bx * 128;
    const int wr = wave >> 2;          // 0..1  (64-row stripe)
    const int wc = wave & 3;           // 0..3  (32-col stripe)
    const int K = DIMM;
    const int NT = K / 64;             // 12

    f32x4 acc[4][2];
#pragma unroll
    for (int i = 0; i < 4; ++i)
#pragma unroll
        for (int j = 0; j < 2; ++j)
#pragma unroll
            for (int r = 0; r < 4; ++r) acc[i][j][r] = 0.f;

    const int sr = lane >> 3;          // 0..7 row within 8-row chunk
    const int scb = (lane & 7) * 16;   // byte col within 128B row

    auto stage = [&](int t) {
        ushort_t* Ab = sm + ((t & 1) ? 16384 : 0);
        ushort_t* Bb = Ab + 8192;
        const int k0 = t * 64;
#pragma unroll
        for (int i = 0; i < 2; ++i) {
            int ch = wave * 2 + i;            // chunk 0..15 (1KB each)
            int r = ch * 8 + sr;              // tile row 0..127
            int cbs = scb ^ ((r & 7) << 4);   // pre-swizzled source col-byte
            int ga = row0 + r; if (ga > M - 1) ga = M - 1;
            gload_lds16(&A[(size_t)ga * K + k0 + (cbs >> 1)], &Ab[ch * 512]);
            gload_lds16(&B[(size_t)(col0 + r) * K + k0 + (cbs >> 1)], &Bb[ch * 512]);
        }
    };

    stage(0);
    for (int t = 0; t < NT; ++t) {
        __syncthreads();                 // drains t's gload_lds; quiesce buf^1
        if (t + 1 < NT) stage(t + 1);    // prefetch next K-tile into buf^1
        ushort_t* Ab = sm + ((t & 1) ? 16384 : 0);
        ushort_t* Bb = Ab + 8192;
#pragma unroll
        for (int ks = 0; ks < 2; ++ks) {
            bf16x8 af[4], bfr[2];
#pragma unroll
            for (int s = 0; s < 4; ++s) {
                int ra = wr * 64 + s * 16 + lo;
                int ca = (ks * 64 + hi * 16) ^ ((ra & 7) << 4);
                af[s] = *(const bf16x8*)&Ab[ra * 64 + (ca >> 1)];
            }
#pragma unroll
            for (int s2 = 0; s2 < 2; ++s2) {
                int rb = wc * 32 + s2 * 16 + lo;
                int cb2 = (ks * 64 + hi * 16) ^ ((rb & 7) << 4);
                bfr[s2] = *(const bf16x8*)&Bb[rb * 64 + (cb2 >> 1)];
            }
#pragma unroll
            for (int i = 0; i < 4; ++i)
#pragma unroll
                for (int j = 0; j < 2; ++j)
                    acc[i][j] = __builtin_amdgcn_mfma_f32_16x16x32_bf16(
                        af[i], bfr[j], acc[i][j], 0, 0, 0);
        }
    }

#pragma unroll
    for (int i = 0; i < 4; ++i) {
#pragma unroll
        for (int reg = 0; reg < 4; ++reg) {
            int r = row0 + wr * 64 + i * 16 + hi * 4 + reg;
            if (r >= M) continue;
#pragma unroll
            for (int j = 0; j < 2; ++j) {
                int c = col0 + wc * 32 + j * 16 + lo;
                float val = acc[i][j][reg] + bias[c];
                if (MODE == 0) {
                    Cf[(size_t)r * DIMM + c] = val;
                } else {
                    int which = c / DIMM;
                    int rem = c - which * DIMM;
                    int head = rem >> 6, d = rem & 63;
                    if (which == 0) {
                        qd[((size_t)head * N_Q + r) * DQH + d] = f2bf(val * QSC);
                    } else {
                        ushort_t* dst = (which == 1) ? kd : vd;
                        dst[((size_t)head * N_Q + r) * HD + d] = f2bf(val);
                    }
                }
            }
        }
    }
}

// ---------------------------------------------------------------------------
// Depthwise 3x3x3 pool (stride 1,2,2, pad 1) + LayerNorm over HD, bf16.
// 4 positions per wave; interior positions take a branch-free 27-tap path.
// ---------------------------------------------------------------------------
__global__ __launch_bounds__(256) void pool_ln2(
    const ushort_t* __restrict__ kin, const ushort_t* __restrict__ vin,
    const float* __restrict__ wkk, const float* __restrict__ wkv,
    const float* __restrict__ gk, const float* __restrict__ bk,
    const float* __restrict__ gv, const float* __restrict__ bv,
    ushort_t* __restrict__ kout, ushort_t* __restrict__ vout)
{
    const int is_k = (blockIdx.y == 0);
    const ushort_t* in = is_k ? kin : vin;
    const float* wk = is_k ? wkk : wkv;
    const float* g  = is_k ? gk : gv;
    const float* b  = is_k ? bk : bv;

    __shared__ float ws_s[27][64];
    const int tid = threadIdx.x;
    for (int e = tid; e < 27 * 64; e += 256) {
        int d = e / 27, tap = e - d * 27;
        ws_s[tap][d] = wk[e];
    }
    __syncthreads();

    const int wave = tid >> 6, lane = tid & 63;
    const float gl = g[lane], bl = b[lane];

#pragma unroll 1
    for (int p4 = 0; p4 < 4; ++p4) {
        const int pos = (blockIdx.x * 4 + wave) * 4 + p4;
        if (pos >= NHEAD * N_KEY) continue;
        const int head = pos / N_KEY;
        const int idx = pos - head * N_KEY;
        const ushort_t* base = in + (size_t)head * N_Q * HD;

        float val;
        if (idx == 0) {
            val = bf2f(base[lane]);
        } else {
            int p = idx - 1;
            int t1 = p / 196;
            int h1 = (p / 14) % 14;
            int w1 = p % 14;
            val = 0.f;
            if (t1 >= 1 && t1 <= 6 && h1 >= 1 && w1 >= 1) {
                int n0 = 1 + ((t1 - 1) * 28 + (2 * h1 - 1)) * 28 + (2 * w1 - 1);
#pragma unroll
                for (int dt = 0; dt < 3; ++dt)
#pragma unroll
                    for (int dh = 0; dh < 3; ++dh)
#pragma unroll
                        for (int dw = 0; dw < 3; ++dw) {
                            int n = n0 + (dt * 784) + (dh * 28) + dw;
                            val += bf2f(base[(size_t)n * HD + lane]) *
                                   ws_s[(dt * 3 + dh) * 3 + dw][lane];
                        }
            } else {
#pragma unroll
                for (int dt = 0; dt < 3; ++dt) {
                    int t = t1 + dt - 1;
                    if (t < 0 || t >= 8) continue;
#pragma unroll
                    for (int dh = 0; dh < 3; ++dh) {
                        int h = 2 * h1 + dh - 1;
                        if (h < 0 || h >= 28) continue;
#pragma unroll
                        for (int dw = 0; dw < 3; ++dw) {
                            int w = 2 * w1 + dw - 1;
                            if (w < 0 || w >= 28) continue;
                            int n = 1 + (t * 28 + h) * 28 + w;
                            val += bf2f(base[(size_t)n * HD + lane]) *
                                   ws_s[(dt * 3 + dh) * 3 + dw][lane];
                        }
                    }
                }
            }
        }
        float mu = val;
#pragma unroll
        for (int off = 1; off < 64; off <<= 1) mu += __shfl_xor(mu, off, 64);
        mu *= (1.f / 64.f);
        float dv = val - mu;
        float var = dv * dv;
#pragma unroll
        for (int off = 1; off < 64; off <<= 1) var += __shfl_xor(var, off, 64);
        var *= (1.f / 64.f);
        float ln = dv * rsqrtf(var + EPSLN) * gl + bl;

        if (!is_k) {
            vout[(size_t)pos * HD + lane] = f2bf(ln);
        } else {
            kout[(size_t)pos * DQH + lane] = f2bf(ln);
            float oh = 0.f;
            if (idx > 0) {
                int p = idx - 1;
                int kt = p / 196, kh = (p / 14) % 14, kw = p % 14;
                if ((lane < 14 && lane == kh) ||
                    (lane >= 14 && lane < 28 && (lane - 14) == kw) ||
                    (lane >= 28 && lane < 36 && (lane - 28) == kt))
                    oh = 1.f;
            }
            kout[(size_t)pos * DQH + 64 + lane] = f2bf(oh);
        }
    }
}

// ---------------------------------------------------------------------------
// rel via MFMA: per (head, 128-qs chunk), G = qhat[:,0:64] @ R[125,64]^T
// (one K=64 step), G*8 -> LDS bf16 [128][136], then gather 36 cols/row into
// qhat rel channels. blockIdx.x==49: cls fix (zero head's q-row-0 rel ch).
// ---------------------------------------------------------------------------
__global__ __launch_bounds__(256) void rel_gemm(
    ushort_t* __restrict__ qhat, const float* __restrict__ rh,
    const float* __restrict__ rw, const float* __restrict__ rt)
{
    __shared__ ushort_t sm[17408];
    const int tid = threadIdx.x;
    const int wave = tid >> 6, lane = tid & 63;
    const int lo = lane & 15, hi = lane >> 4;
    const int head = blockIdx.y;

    if (blockIdx.x == 49) {
        if (tid < 64) qhat[((size_t)head * N_Q) * DQH + 64 + tid] = 0;
        return;
    }
    const int qs0 = blockIdx.x * 128;
    ushort_t* Al = sm;
    ushort_t* Bl = sm + 8192;

    const int sr = lane >> 3;
    const int scb = (lane & 7) * 16;
#pragma unroll
    for (int i = 0; i < 4; ++i) {
        int ch = wave * 4 + i;
        int rl = ch * 8 + sr;
        int cbs = scb ^ ((rl & 7) << 4);
        gload_lds16(&qhat[((size_t)head * N_Q + 1 + qs0 + rl) * DQH + (cbs >> 1)],
                    &Al[ch * 512]);
    }
#pragma unroll
    for (int i = 0; i < 4; ++i) {
        int u = tid + i * 256;
        int r = u >> 3, cg = u & 7;
        ushort_t tmp[8];
        if (r < 125) {
            const float* src = (r < 55) ? &rh[r * 64 + cg * 8]
                             : (r < 110) ? &rw[(r - 55) * 64 + cg * 8]
                                         : &rt[(r - 110) * 64 + cg * 8];
#pragma unroll
            for (int k = 0; k < 8; ++k) tmp[k] = f2bf(src[k]);
        } else {
#pragma unroll
            for (int k = 0; k < 8; ++k) tmp[k] = 0;
        }
        *(uint4*)&Bl[r * 64 + ((cg ^ (r & 7)) * 8)] = *(uint4*)tmp;
    }
    __syncthreads();

    f32x4 acc[2][8];
#pragma unroll
    for (int s = 0; s < 2; ++s)
#pragma unroll
        for (int cs = 0; cs < 8; ++cs)
#pragma unroll
            for (int r = 0; r < 4; ++r) acc[s][cs][r] = 0.f;

#pragma unroll
    for (int kk = 0; kk < 2; ++kk) {
        bf16x8 af[2];
#pragma unroll
        for (int s = 0; s < 2; ++s) {
            int ra = wave * 32 + s * 16 + lo;
            int ca = (kk * 32 + hi * 8) ^ ((ra & 7) * 8);
            af[s] = *(const bf16x8*)&Al[ra * 64 + ca];
        }
#pragma unroll
        for (int cs = 0; cs < 8; ++cs) {
            int rb = cs * 16 + lo;
            int cb = (kk * 32 + hi * 8) ^ ((rb & 7) * 8);
            bf16x8 bv = *(const bf16x8*)&Bl[rb * 64 + cb];
            acc[0][cs] = __builtin_amdgcn_mfma_f32_16x16x32_bf16(af[0], bv, acc[0][cs], 0, 0, 0);
            acc[1][cs] = __builtin_amdgcn_mfma_f32_16x16x32_bf16(af[1], bv, acc[1][cs], 0, 0, 0);
        }
    }
    __syncthreads();

#pragma unroll
    for (int s = 0; s < 2; ++s)
#pragma unroll
        for (int cs = 0; cs < 8; ++cs)
#pragma unroll
            for (int reg = 0; reg < 4; ++reg) {
                int rl = wave * 32 + s * 16 + hi * 4 + reg;
                sm[rl * 136 + cs * 16 + lo] = cvt_native(acc[s][cs][reg] * 8.0f);
            }
    __syncthreads();

#pragma unroll 1
    for (int it = 0; it < 18; ++it) {
        int idx = it * 64 + lane;
        int r = idx / 36;
        int j = idx - r * 36;
        int qs = qs0 + wave * 32 + r;
        int t = qs / 784, h = (qs / 28) % 28, w = qs % 28;
        int ridx;
        if (j < 14)      ridx = h - 2 * j + 26;
        else if (j < 28) ridx = 55 + (w - 2 * (j - 14) + 26);
        else             ridx = 110 + (t - (j - 28) + 7);
        ushort_t val = sm[(wave * 32 + r) * 136 + ridx];
        qhat[((size_t)head * N_Q + 1 + qs) * DQH + 64 + j] = val;
    }
}

// ---------------------------------------------------------------------------
// Fused flash attention: pipeline + 4-bit Ks swizzle + setprio + hoisted
// addressing + XCD q-tile remap + raw v_exp softmax + tree max + l-via-MFMA
// with register-constant ones fragment. QBLK=160, 640 thr, 480 blocks.
// ---------------------------------------------------------------------------
__global__ __launch_bounds__(640) void attn_mfma(
    const ushort_t* __restrict__ qhat, const ushort_t* __restrict__ khat,
    const ushort_t* __restrict__ vp, ushort_t* __restrict__ aout)
{
    // LDS (ushorts): Ks0[0,8192) Ks1[8192,16384) Vt0[16384,20480)
    // Vt1[20480,24576). Epilogue Ob aliases [0, 14080).
    __shared__ ushort_t smem[24576];

    const int tid = threadIdx.x;
    const int wave = tid >> 6, lane = tid & 63;
    const int lo = lane & 15, hi = lane >> 4;
    const int head = blockIdx.y;
    const int q0 = xcd_swz(blockIdx.x, NQT) * QBLK;   // XCD-chunked q-tiles
    const int qrow = q0 + wave * 16 + lo;

    const ushort_t* khat_h = khat + (size_t)head * N_KEY * DQH;
    const ushort_t* vp_h   = vp + (size_t)head * N_KEY * HD;

    bf16x8 qa[4];
    if (qrow < N_Q) {
        const ushort_t* qpt = &qhat[((size_t)head * N_Q + qrow) * DQH];
#pragma unroll
        for (int j = 0; j < 4; ++j) qa[j] = *(const bf16x8*)&qpt[j * 32 + hi * 8];
    } else {
#pragma unroll
        for (int j = 0; j < 4; ++j)
#pragma unroll
            for (int e = 0; e < 8; ++e) qa[j][e] = (__bf16)0.0f;
    }

    // register-constant lsum A-fragment: rows 64..79 of V^T -> ones iff lo==0
    union { ushort_t u16[8]; bf16x8 v; } onesf;
#pragma unroll
    for (int e = 0; e < 8; ++e) onesf.u16[e] = (lo == 0) ? (ushort_t)0x3F80 : 0;

    float m_run = -1e30f;
    f32x4 o[4], olsum;
#pragma unroll
    for (int i = 0; i < 4; ++i)
#pragma unroll
        for (int r = 0; r < 4; ++r) o[i][r] = 0.f;
#pragma unroll
    for (int r = 0; r < 4; ++r) olsum[r] = 0.f;

    const bool oddh = (hi & 1) != 0;
    const bool toph = (hi >> 1) != 0;
    const int NT = (N_KEY + 63) / 64;   // 25

    const int vkey = tid & 63, vd0 = ((tid >> 6) & 7) * 8;
    uint4 vv;

    int ksrd[4][4];
#pragma unroll
    for (int kk = 0; kk < 4; ++kk)
#pragma unroll
        for (int sub = 0; sub < 4; ++sub)
            ksrd[kk][sub] = (sub * 16 + lo) * 128 + ((kk * 32 + hi * 8) ^ (lo * 8));
    int vtrd[2][4];
#pragma unroll
    for (int kh2 = 0; kh2 < 2; ++kh2)
#pragma unroll
        for (int sd = 0; sd < 4; ++sd)
            vtrd[kh2][sd] = (sd * 16 + lo) * 64 + ((kh2 * 32 + hi * 8) ^ ((lo & 7) * 8));
    int vwr[8];
#pragma unroll
    for (int j = 0; j < 8; ++j) vwr[j] = (vd0 + j) * 64 + (vkey ^ (j * 8));

    auto stage = [&](int t) {
        const int m0 = t * 64;
        if (wave < 8) {
            ushort_t* Ksb = smem + ((t & 1) << 13);
#pragma unroll
            for (int i = 0; i < 2; ++i) {
                int ch = wave * 2 + i;
                int kr = ch * 4 + hi;
                int cb = (lo * 16) ^ ((kr & 15) << 4);
                int gm = m0 + kr; if (gm > N_KEY - 1) gm = N_KEY - 1;
                gload_lds16(&khat_h[(gm << 7) + (cb >> 1)], &Ksb[ch * 512]);
            }
            int gm = m0 + vkey; if (gm > N_KEY - 1) gm = N_KEY - 1;
            vv = *(const uint4*)&vp_h[(gm << 6) + vd0];
        }
    };

    stage(0);
#pragma unroll 2
    for (int t = 0; t < NT; ++t) {
        const int m0 = t * 64;
        ushort_t* Ksb = smem + ((t & 1) << 13);
        ushort_t* Vtb = smem + 16384 + ((t & 1) << 12);

        if (wave < 8) {
            ushort_t tmp[8];
            *(uint4*)tmp = vv;
#pragma unroll
            for (int j = 0; j < 8; ++j) Vtb[vwr[j]] = tmp[j];
        }
        __syncthreads();
        if (t + 1 < NT) stage(t + 1);

        f32x4 s[4];
#pragma unroll
        for (int sub = 0; sub < 4; ++sub)
#pragma unroll
            for (int r = 0; r < 4; ++r) s[sub][r] = 0.f;
        __builtin_amdgcn_s_setprio(1);
#pragma unroll
        for (int kk = 0; kk < 4; ++kk) {
#pragma unroll
            for (int sub = 0; sub < 4; ++sub) {
                bf16x8 kf = *(const bf16x8*)&Ksb[ksrd[kk][sub]];
                s[sub] = __builtin_amdgcn_mfma_f32_16x16x32_bf16(kf, qa[kk], s[sub], 0, 0, 0);
            }
        }
        __builtin_amdgcn_s_setprio(0);

        if (m0 + 64 > N_KEY) {
#pragma unroll
            for (int sub = 0; sub < 4; ++sub)
#pragma unroll
                for (int reg = 0; reg < 4; ++reg)
                    if (m0 + sub * 16 + hi * 4 + reg >= N_KEY) s[sub][reg] = -1e30f;
        }

        // tree max (depth 4, max3-fusable)
        float a0 = fmaxf(s[0][0], s[0][1]), a1 = fmaxf(s[0][2], s[0][3]);
        float a2 = fmaxf(s[1][0], s[1][1]), a3 = fmaxf(s[1][2], s[1][3]);
        float a4 = fmaxf(s[2][0], s[2][1]), a5 = fmaxf(s[2][2], s[2][3]);
        float a6 = fmaxf(s[3][0], s[3][1]), a7 = fmaxf(s[3][2], s[3][3]);
        float b0 = fmaxf(a0, a1), b1 = fmaxf(a2, a3);
        float b2 = fmaxf(a4, a5), b3 = fmaxf(a6, a7);
        float rm = fmaxf(fmaxf(b0, b1), fmaxf(b2, b3));
        rm = fmaxf(rm, __shfl_xor(rm, 16));
        rm = fmaxf(rm, __shfl_xor(rm, 32));

        if (__any(rm - m_run > DEFER_THR)) {
            float mnew = fmaxf(m_run, rm);
            float corr = fexp2(m_run - mnew);
#pragma unroll
            for (int sub = 0; sub < 4; ++sub)
#pragma unroll
                for (int reg = 0; reg < 4; ++reg)
                    s[sub][reg] = fexp2(s[sub][reg] - mnew);
            m_run = mnew;
#pragma unroll
            for (int i = 0; i < 4; ++i)
#pragma unroll
                for (int r = 0; r < 4; ++r) o[i][r] *= corr;
            olsum[0] *= corr;
        } else {
#pragma unroll
            for (int sub = 0; sub < 4; ++sub)
#pragma unroll
                for (int reg = 0; reg < 4; ++reg)
                    s[sub][reg] = fexp2(s[sub][reg] - m_run);
        }

#pragma unroll
        for (int kh2 = 0; kh2 < 2; ++kh2) {
            uint_t x0a = pk2(s[2 * kh2][0], s[2 * kh2][1]);
            uint_t x0b = pk2(s[2 * kh2][2], s[2 * kh2][3]);
            uint_t x1a = pk2(s[2 * kh2 + 1][0], s[2 * kh2 + 1][1]);
            uint_t x1b = pk2(s[2 * kh2 + 1][2], s[2 * kh2 + 1][3]);
            uint_t y0a = __shfl_xor(x0a, 16), y0b = __shfl_xor(x0b, 16);
            uint_t y1a = __shfl_xor(x1a, 16), y1b = __shfl_xor(x1b, 16);
            uint_t c0[4] = { oddh ? y0a : x0a, oddh ? y0b : x0b,
                             oddh ? x0a : y0a, oddh ? x0b : y0b };
            uint_t c1[4] = { oddh ? y1a : x1a, oddh ? y1b : x1b,
                             oddh ? x1a : y1a, oddh ? x1b : y1b };
            union { uint_t u[4]; bf16x8 v; } pw;
#pragma unroll
            for (int i2 = 0; i2 < 4; ++i2) {
                uint_t send = oddh ? c0[i2] : c1[i2];
                uint_t f = __shfl_xor(send, 32);
                pw.u[i2] = (toph != oddh) ? f : (oddh ? c1[i2] : c0[i2]);
            }
            __builtin_amdgcn_s_setprio(1);
#pragma unroll
            for (int sub_d = 0; sub_d < 4; ++sub_d) {
                bf16x8 vf = *(const bf16x8*)&Vtb[vtrd[kh2][sub_d]];
                o[sub_d] = __builtin_amdgcn_mfma_f32_16x16x32_bf16(vf, pw.v, o[sub_d], 0, 0, 0);
            }
            // l-sum via register-constant ones fragment (no LDS read)
            olsum = __builtin_amdgcn_mfma_f32_16x16x32_bf16(onesf.v, pw.v, olsum, 0, 0, 0);
            __builtin_amdgcn_s_setprio(0);
        }
    }

    // epilogue: l lives in olsum[0] of hi==0 lanes (row 64, col=lo); broadcast
    float lsum = __shfl(olsum[0], lo);
    ushort_t* Ob = smem + wave * (16 * 88);
    __syncthreads();
    float inv = 1.f / lsum;
#pragma unroll
    for (int sub_d = 0; sub_d < 4; ++sub_d)
#pragma unroll
        for (int reg = 0; reg < 4; ++reg)
            Ob[lo * 88 + sub_d * 16 + hi * 4 + reg] = cvt_native(o[sub_d][reg] * inv);
    __syncthreads();
#pragma unroll
    for (int i = 0; i < 2; ++i) {
        int e = lane + i * 64;
        int r = e >> 3, cc = e & 7;
        int gq = q0 + wave * 16 + r;
        if (gq < N_Q) {
            uint4 ov = *(const uint4*)&Ob[r * 88 + cc * 8];
            *(uint4*)&aout[(size_t)gq * DIMM + head * HD + cc * 8] = ov;
        }
    }
}

// ---------------------------------------------------------------------------
extern "C" void kernel_launch(void* const* d_in, const int* in_sizes, int n_in,
                              void* d_out, int out_size, void* d_ws, size_t ws_size,
                              hipStream_t stream)
{
    const float* x      = (const float*)d_in[0];
    const float* qkv_w  = (const float*)d_in[1];
    const float* qkv_b  = (const float*)d_in[2];
    const float* proj_w = (const float*)d_in[3];
    const float* proj_b = (const float*)d_in[4];
    const float* pkw    = (const float*)d_in[5];
    const float* pvw    = (const float*)d_in[6];
    const float* nkg    = (const float*)d_in[7];
    const float* nkb    = (const float*)d_in[8];
    const float* nvg    = (const float*)d_in[9];
    const float* nvb    = (const float*)d_in[10];
    const float* rph    = (const float*)d_in[11];
    const float* rpw    = (const float*)d_in[12];
    const float* rpt    = (const float*)d_in[13];

    const size_t SZ_X     = (size_t)N_Q * DIMM;
    const size_t SZ_QKVW  = (size_t)3 * DIMM * DIMM;
    const size_t SZ_PROJW = (size_t)DIMM * DIMM;
    const size_t SZ_QHAT  = (size_t)NHEAD * N_Q * DQH;
    const size_t SZ_KV    = (size_t)NHEAD * N_Q * HD;
    const size_t SZ_KHAT  = (size_t)NHEAD * N_KEY * DQH;
    const size_t SZ_VPO   = (size_t)NHEAD * N_KEY * HD;

    ushort_t* xb     = (ushort_t*)d_ws;
    ushort_t* qkvwb  = xb + SZ_X;
    ushort_t* projwb = qkvwb + SZ_QKVW;
    ushort_t* qhat   = projwb + SZ_PROJW;
    ushort_t* kb     = qhat + SZ_QHAT;
    ushort_t* vb     = kb + SZ_KV;
    ushort_t* khat   = vb + SZ_KV;
    ushort_t* vpo    = khat + SZ_KHAT;
    ushort_t* aout   = vpo + SZ_VPO;
    float*    outp   = (float*)d_out;

    // 0) convert inputs to bf16
    cvt3_bf16<<<2048, 256, 0, stream>>>(x, qkv_w, proj_w, xb,
                                        (int)(SZ_X / 8), (int)(SZ_QKVW / 8),
                                        (int)(SZ_PROJW / 8));
    // 1) qkv GEMM (pipelined, XCD-swizzled)
    gemm_pipe<1><<<dim3(18, 50), 512, 0, stream>>>(xb, qkvwb, qkv_b, N_Q,
                                                   nullptr, qhat, kb, vb);
    // 2) pool + LN
    pool_ln2<<<dim3((NHEAD * N_KEY + 15) / 16, 2), 256, 0, stream>>>(
        kb, vb, pkw, pvw, nkg, nkb, nvg, nvb, khat, vpo);
    // 3) rel-pos via MFMA GEMM + gather
    rel_gemm<<<dim3(50, NHEAD), 256, 0, stream>>>(qhat, rph, rpw, rpt);
    // 4) fused attention (QBLK=160, register-constant l-sum fragment)
    attn_mfma<<<dim3(NQT, NHEAD), 640, 0, stream>>>(qhat, khat, vpo, aout);
    // 5) proj GEMM (pipelined, XCD-swizzled)
    gemm_pipe<0><<<dim3(6, 50), 512, 0, stream>>>(aout, projwb, proj_b, N_Q,
                                                  outp, nullptr, nullptr, nullptr);
}